// Round 17
// baseline (175.565 us; speedup 1.0000x reference)
//
#include <hip/hip_runtime.h>

// LIF net on MI355X.  R17 = R16 with BK=64 gemm (half the barriers).
//  1. convert_W: Bt[13][256][64] bf16 (relu, 8-slot swizzled, K-pad 832) + wrelu
//  2. gemm_hidden: 256 blocks (b, t-half) x 1024 thr, tile 256m x 256n, BK=64,
//     1KB A-runs, counted vmcnt(4) barriers (13 iters), XCD pair-swizzle.
//     LDS 128KB: As dbuf 2x32KB + Bs dbuf 2x32KB.  -> Ih[b][h][512] bf16
//  3. scan_dot: fused wave-parallel LIF scan + MFMA dot -> IoP[b][t][4][10]
//  4. lif_out: per-b: sum 4 partials -> segmented v_o scan -> outputs
// ws: wrelu @0 | Bt @16KB (416KB) | Ih @512KB (33.55MB) | IoP (10.49MB)

typedef __attribute__((ext_vector_type(4))) float  floatx4;
typedef __attribute__((ext_vector_type(8))) short  shortx8;
typedef unsigned short u16;
typedef unsigned int   u32;

#define B_   128
#define NIN  784
#define NH   256
#define NO   10
#define T_   500
#define NK   13            // K padded to 832, tiles of 64
#define SROW 520           // scan_dot sbuf row stride (u16)

__device__ __forceinline__ u16 f2bf(float f) {
    union { float f; u32 u; } x; x.f = f;
    u32 r = x.u + 0x7FFFu + ((x.u >> 16) & 1u);   // RNE
    return (u16)(r >> 16);
}
__device__ __forceinline__ float bf2f(u16 u) {
    union { u32 u; float f; } x; x.u = ((u32)u) << 16; return x.f;
}
__device__ __forceinline__ float sigmoid5(float v) {
    return 1.0f / (1.0f + __expf(-5.0f * (v - 1.0f)));
}

__device__ __forceinline__ void gload16(const u16* g, u16* l) {
    __builtin_amdgcn_global_load_lds(
        (const __attribute__((address_space(1))) unsigned int*)(const void*)g,
        (__attribute__((address_space(3))) unsigned int*)(void*)l, 16, 0, 0);
}

// ---------- Pre-pass: Bt[kt][n][(kk&7) + ((kk>>3 ^ n&7)<<3)] bf16 + wrelu ----------
__global__ void convert_W(const float* __restrict__ w_ih,
                          const float* __restrict__ w_ho,
                          u16* __restrict__ Bt, float* __restrict__ wrelu) {
    if (blockIdx.x == NK * 64) {
        for (int i = threadIdx.x; i < NH * NO; i += 256)
            wrelu[i] = fmaxf(0.f, w_ho[i]);
        return;
    }
    const int k = blockIdx.x;           // 0..831
    const int n = threadIdx.x;          // 0..255
    const float f = (k < NIN) ? fmaxf(0.f, w_ih[k * NH + n]) : 0.f;
    const int kt = k >> 6, kk = k & 63;
    const int slot = (kk >> 3) ^ (n & 7);
    Bt[(size_t)kt * 16384 + n * 64 + slot * 8 + (kk & 7)] = f2bf(f);
}

// ---------- hidden GEMM: 256m x 256n, BK=64, 13 counted barriers ----------
__global__ __launch_bounds__(1024, 4) void gemm_hidden(
    const float* __restrict__ spikes,   // [128][784][500] f32
    const u16* __restrict__ Bt,         // [13][256][64] bf16 swizzled
    u16* __restrict__ Ih)               // [128][256][512] bf16
{
    __shared__ u16 SH[65536];           // 128KB
    u16* AS0 = SH;                      // 16384 u16 = 32KB each
    u16* AS1 = SH + 16384;
    u16* BS0 = SH + 32768;
    u16* BS1 = SH + 49152;

    const int tid = threadIdx.x;
    // XCD pair-swizzle: (b, th=0/1) adjacent dispatch slots on one XCD
    const int xcd  = blockIdx.x & 7;
    const int slot = blockIdx.x >> 3;   // 0..31
    const int b    = xcd * 16 + (slot >> 1);
    const int th   = slot & 1;
    const int t0   = th * 256;

    // A staging: kq=tid>>6 (0..15) -> k-rows 4kq..4kq+3; tg=tid&63 -> t=t0+4tg
    // Each wave-load = 64 lanes x 16B = one 1KB contiguous t-run of a k-row.
    const int kq = tid >> 6, tg = tid & 63;
    const int tloc = t0 + tg * 4;
    const bool t_ok = (tloc <= 496);
    const float* sbase = spikes + (size_t)b * (NIN * T_) + tloc;
    const int oct  = kq >> 1;           // k-octet 0..7
    const int koff = (4 * kq) & 7;      // 0 or 4

    // MFMA roles: 16 waves = 4 wm x 4 wn, wave tile 64m x 64n
    const int lane = tid & 63, wid = tid >> 6;
    const int wm = wid >> 2, wn = wid & 3;
    const int lg = lane >> 4, lr = lane & 15;
    int mBase[4], mx[4], nBase[4], nx[4];
#pragma unroll
    for (int mi = 0; mi < 4; ++mi) {
        const int m = wm * 64 + mi * 16 + lr;
        mBase[mi] = m * 64;  mx[mi] = m & 7;
    }
#pragma unroll
    for (int ni = 0; ni < 4; ++ni) {
        const int n = wn * 64 + ni * 16 + lr;
        nBase[ni] = n * 64;  nx[ni] = n & 7;
    }

    floatx4 acc[4][4];
#pragma unroll
    for (int i = 0; i < 4; ++i)
#pragma unroll
        for (int j = 0; j < 4; ++j) acc[i][j] = (floatx4)0.f;

#define LOADA(va, itv) { _Pragma("unroll") for (int r = 0; r < 4; ++r) {       \
        const int gk = (itv) * 64 + 4 * kq + r;                                \
        const bool ok = t_ok && (gk < NIN);                                    \
        const float* p = ok ? (sbase + (size_t)gk * T_) : sbase;               \
        floatx4 u = *(const floatx4*)p;                                        \
        va[r] = ok ? u : (floatx4)0.f; } }

#define WRITEA(ASX, va) { _Pragma("unroll") for (int j = 0; j < 4; ++j) {      \
        const int m = tg * 4 + j;                                              \
        const int slt = oct ^ (m & 7);                                         \
        uint2 pk;                                                              \
        pk.x = (u32)f2bf(va[0][j]) | ((u32)f2bf(va[1][j]) << 16);              \
        pk.y = (u32)f2bf(va[2][j]) | ((u32)f2bf(va[3][j]) << 16);              \
        *(uint2*)&(ASX)[m * 64 + slt * 8 + koff] = pk; } }

#define STAGEB(BSX, itv) {                                                     \
        const u16* src = Bt + (size_t)(itv) * 16384;                           \
        gload16(src + tid * 8,        (BSX) + tid * 8);                        \
        gload16(src + 8192 + tid * 8, (BSX) + 8192 + tid * 8); }

#define MFMAIT(ASX, BSX) { _Pragma("unroll") for (int ks = 0; ks < 2; ++ks) {  \
        shortx8 af[4], bf[4];                                                  \
        _Pragma("unroll") for (int mi = 0; mi < 4; ++mi)                       \
            af[mi] = *(const shortx8*)&(ASX)[mBase[mi] +                       \
                        (((ks * 4 + lg) ^ mx[mi]) << 3)];                      \
        _Pragma("unroll") for (int ni = 0; ni < 4; ++ni)                       \
            bf[ni] = *(const shortx8*)&(BSX)[nBase[ni] +                       \
                        (((ks * 4 + lg) ^ nx[ni]) << 3)];                      \
        _Pragma("unroll") for (int mi = 0; mi < 4; ++mi)                       \
        _Pragma("unroll") for (int ni = 0; ni < 4; ++ni)                       \
            acc[mi][ni] = __builtin_amdgcn_mfma_f32_16x16x32_bf16(             \
                af[mi], bf[ni], acc[mi][ni], 0, 0, 0); } }

// counted barrier: retires B stage (oldest 2), leaves A prefetch (4) in flight
#define CBAR4 { asm volatile("s_waitcnt vmcnt(4) lgkmcnt(0)" ::: "memory");    \
                __builtin_amdgcn_s_barrier(); }
#define LBAR  { asm volatile("s_waitcnt lgkmcnt(0)" ::: "memory");             \
                __builtin_amdgcn_s_barrier(); }

    floatx4 vaP[4];

    // prologue: A0 -> AS0, B0 issued, A1 in flight
    LOADA(vaP, 0);
    WRITEA(AS0, vaP);                   // compiler waits vaP loads only
    STAGEB(BS0, 0);
    LOADA(vaP, 1);
    CBAR4;                              // B0 done; A1 flying

    // body: 12 iters (6 x 2-unroll); iter it computes tile it
    for (int it = 0; it < 12; it += 2) {
        STAGEB(BS1, it + 1);
        WRITEA(AS1, vaP);               // waits A(it+1) (older than B)
        LOADA(vaP, it + 2);
        MFMAIT(AS0, BS0);
        CBAR4;                          // B(it+1) done; A(it+2) flying

        STAGEB(BS0, it + 2);
        WRITEA(AS0, vaP);
        LOADA(vaP, it + 3);             // it+3 <= 13: OOB tile loads clamp to 0
        MFMAIT(AS1, BS1);
        CBAR4;
    }
    MFMAIT(AS0, BS0);                   // tile 12
    LBAR;                               // LDS reads done; SH free for Cs

    // ---- epilogue: 2 rounds via Cs[256 n][128 m] (64KB, aliases SH) ----
    u16* Cs = SH;
#pragma unroll
    for (int h = 0; h < 2; ++h) {
        if ((wm >> 1) == h) {
#pragma unroll
            for (int mi = 0; mi < 4; ++mi)
#pragma unroll
                for (int rr = 0; rr < 2; ++rr) {
                    const int mloc = (wm & 1) * 64 + mi * 16 + lg * 4 + rr * 2;
#pragma unroll
                    for (int ni = 0; ni < 4; ++ni) {
                        const int n = wn * 64 + ni * 16 + lr;
                        const u32 pk = (u32)f2bf(acc[mi][ni][rr * 2]) |
                                       ((u32)f2bf(acc[mi][ni][rr * 2 + 1]) << 16);
                        *(u32*)&Cs[n * 128 + (mloc ^ ((n & 7) << 3))] = pk;
                    }
                }
        }
        LBAR;
        {
            const int n = tid >> 2, ms = tid & 3;
            u16* gdst = Ih + ((size_t)b * 256 + n) * 512 + t0 + h * 128 + ms * 32;
#pragma unroll
            for (int j = 0; j < 4; ++j) {
                const uint4 v = *(const uint4*)&Cs[n * 128 +
                                ((ms * 32 + j * 8) ^ ((n & 7) << 3))];
                *(uint4*)(gdst + j * 8) = v;
            }
        }
        LBAR;
    }
#undef LOADA
#undef WRITEA
#undef STAGEB
#undef MFMAIT
#undef CBAR4
#undef LBAR
}

// ---------- fused: parallel hidden LIF scan + output dot ----------
__global__ __launch_bounds__(512, 2) void scan_dot(
    const u16* __restrict__ Ih,         // [128][256][512] bf16
    const float* __restrict__ wr,       // [256][10] relu'd f32
    float* __restrict__ IoP)            // [128][512][4][10] f32
{
    __shared__ u16 sbuf[64 * SROW];     // 66.6KB
    const int tid = threadIdx.x;
    const int hg  = blockIdx.x & 3;
    const int b   = blockIdx.x >> 2;
    const int h0  = hg * 64;
    const int lane = tid & 63, w = tid >> 6;

    // ---- phase 1: scan 8 rows per wave (affine shfl composition) ----
    for (int r = 0; r < 8; ++r) {
        const int hl = w * 8 + r;
        const u16* p = Ih + ((size_t)b * 256 + h0 + hl) * 512 + lane * 8;
        shortx8 xv = *(const shortx8*)p;
        float I[8];
#pragma unroll
        for (int j = 0; j < 8; ++j) I[j] = bf2f((u16)xv[j]);
        float z = 0.f;
#pragma unroll
        for (int j = 0; j < 8; ++j) z += (I[j] - z) * 0.1f;
        float A = 0.43046721f, Bv = z;             // 0.9^8
#pragma unroll
        for (int d = 1; d < 64; d <<= 1) {
            const float Au = __shfl_up(A, d);
            const float Bu = __shfl_up(Bv, d);
            if (lane >= d) { Bv = fmaf(A, Bu, Bv); A *= Au; }
        }
        float v = __shfl_up(Bv, 1);
        if (lane == 0) v = 0.f;
        shortx8 sv;
#pragma unroll
        for (int j = 0; j < 8; ++j) {
            v += (I[j] - v) * 0.1f;
            sv[j] = (short)f2bf(sigmoid5(v));
        }
        *(shortx8*)&sbuf[hl * SROW + lane * 8] = sv;
    }
    __syncthreads();

    // ---- phase 2: dot via MFMA.  A[m=t][k=hl], B[k=hl][n=o] ----
    const int lg = lane >> 4, lr = lane & 15;
    shortx8 bw0, bw1;
#pragma unroll
    for (int j = 0; j < 8; ++j) {
        const int hA = h0 + lg * 8 + j;
        const int hB = hA + 32;
        bw0[j] = (short)((lr < NO) ? f2bf(wr[hA * NO + lr]) : 0);
        bw1[j] = (short)((lr < NO) ? f2bf(wr[hB * NO + lr]) : 0);
    }
#pragma unroll
    for (int fi = 0; fi < 4; ++fi) {
        const int tf = w * 4 + fi;
        const int t  = tf * 16 + lr;
        floatx4 acc = (floatx4)0.f;
#pragma unroll
        for (int ks = 0; ks < 2; ++ks) {
            union { shortx8 s; u32 d[4]; } u;
#pragma unroll
            for (int q = 0; q < 4; ++q) {
                const int h1 = ks * 32 + lg * 8 + 2 * q;
                u.d[q] = (u32)sbuf[h1 * SROW + t] |
                         ((u32)sbuf[(h1 + 1) * SROW + t] << 16);
            }
            acc = __builtin_amdgcn_mfma_f32_16x16x32_bf16(
                u.s, (ks == 0) ? bw0 : bw1, acc, 0, 0, 0);
        }
        if (lr < NO) {
#pragma unroll
            for (int rr = 0; rr < 4; ++rr) {
                const int tt = tf * 16 + lg * 4 + rr;
                IoP[(((size_t)b * 512 + tt) * 4 + hg) * NO + lr] = acc[rr];
            }
        }
    }
}

// ---------- output LIF scan: sum 4 partials + segmented scan ----------
__global__ __launch_bounds__(256) void lif_out(
    const float* __restrict__ IoP,      // [128][512][4][10] f32
    float* __restrict__ out)
{
    __shared__ float Io[T_ * NO];       // 20KB
    __shared__ float vend[25][NO], vstart[25][NO], psum[25][NO];
    const int b = blockIdx.x, tid = threadIdx.x;

    for (int i = tid; i < T_ * NO; i += 256) {
        const int t = i / NO, o = i - t * NO;
        const float* q = IoP + ((size_t)b * 512 + t) * 40 + o;
        Io[i] = (q[0] + q[10]) + (q[20] + q[30]);
    }
    __syncthreads();

    const int seg = tid / NO, o = tid - seg * NO;
    if (tid < 250) {
        float v = 0.f;
#pragma unroll
        for (int j = 0; j < 20; ++j)
            v += (Io[(seg * 20 + j) * NO + o] - v) * 0.1f;
        vend[seg][o] = v;
    }
    __syncthreads();
    if (tid < NO) {
        float vs = 0.f;
#pragma unroll
        for (int sg = 0; sg < 25; ++sg) {
            vstart[sg][tid] = vs;
            vs = vend[sg][tid] + 0.12157665459f * vs;   // 0.9^20
        }
    }
    __syncthreads();
    if (tid < 250) {
        float v = vstart[seg][o], ps = 0.f;
#pragma unroll
        for (int j = 0; j < 20; ++j) {
            const int t = seg * 20 + j;
            v += (Io[t * NO + o] - v) * 0.1f;
            const float sv = sigmoid5(v);
            out[(size_t)b * (NO * T_) + (size_t)o * T_ + t] = sv;
            ps += sv;
        }
        psum[seg][o] = ps;
    }
    __syncthreads();
    if (tid < NO) {
        float tot = 0.f;
#pragma unroll
        for (int sg = 0; sg < 25; ++sg) tot += psum[sg][tid];
        out[(size_t)(B_ * NO) * T_ + b * NO + tid] = tot * (1.0f / T_);
    }
}

extern "C" void kernel_launch(void* const* d_in, const int* in_sizes, int n_in,
                              void* d_out, int out_size, void* d_ws, size_t ws_size,
                              hipStream_t stream) {
    (void)in_sizes; (void)n_in; (void)out_size; (void)ws_size;
    const float* spikes = (const float*)d_in[0];   // [128][784][500]
    const float* w_ih   = (const float*)d_in[1];   // [784][256]
    const float* w_ho   = (const float*)d_in[2];   // [256][10]
    float* out = (float*)d_out;

    float* wrelu = (float*)d_ws;                              // 10KB @0
    u16*   Bt    = (u16*)((char*)d_ws + 16384);               // 416KB
    u16*   Ih    = (u16*)((char*)d_ws + 524288);              // 33.55MB
    float* IoP   = (float*)((char*)d_ws + 524288 + 33554432); // 10.49MB

    convert_W  <<<NK * 64 + 1, 256, 0, stream>>>(w_ih, w_ho, Bt, wrelu);
    gemm_hidden<<<256, 1024, 0, stream>>>(spikes, Bt, Ih);
    scan_dot   <<<512, 512, 0, stream>>>(Ih, wrelu, IoP);
    lif_out    <<<B_, 256, 0, stream>>>(IoP, out);
}

// Round 18
// 81.399 us; speedup vs baseline: 2.1568x; 2.1568x over previous
//
#include <hip/hip_runtime.h>

// LIF net on MI355X.  R18 = R16 verbatim (revert of R17's spilling BK=64).
//  1. convert_W: Bt[25][256][32] bf16 (relu, slot-swizzled, K-pad 800) + wrelu
//  2. gemm_hidden: 256 blocks (b, t-half) x 1024 thr, tile 256m x 256n, BK=32,
//     1KB A-runs, counted vmcnt(2) barriers; XCD swizzle pairs (b,0),(b,1)
//     on one XCD.  -> Ih[b][h][512] bf16
//  3. scan_dot: 512 blocks (b, h-group of 64) x 512 thr: wave-parallel LIF
//     scan (8 rows/wave) -> s bf16 in LDS [64][520] -> MFMA vs w_ho frags
//     -> partial IoP[b][t][4][10] f32.
//  4. lif_out: per-b: sum 4 partials -> segmented v_o scan -> outputs
// ws: wrelu @0 | Bt @16KB | Ih @512KB (33.55MB) | IoP @34.08MB (10.49MB)

typedef __attribute__((ext_vector_type(4))) float  floatx4;
typedef __attribute__((ext_vector_type(8))) short  shortx8;
typedef unsigned short u16;
typedef unsigned int   u32;

#define B_   128
#define NIN  784
#define NH   256
#define NO   10
#define T_   500
#define NK   25            // K padded to 800, tiles of 32
#define SROW 520           // sbuf row stride (u16): 1040B, 16B-aligned rows

__device__ __forceinline__ u16 f2bf(float f) {
    union { float f; u32 u; } x; x.f = f;
    u32 r = x.u + 0x7FFFu + ((x.u >> 16) & 1u);   // RNE
    return (u16)(r >> 16);
}
__device__ __forceinline__ float bf2f(u16 u) {
    union { u32 u; float f; } x; x.u = ((u32)u) << 16; return x.f;
}
__device__ __forceinline__ float sigmoid5(float v) {
    return 1.0f / (1.0f + __expf(-5.0f * (v - 1.0f)));
}

__device__ __forceinline__ void gload16(const u16* g, u16* l) {
    __builtin_amdgcn_global_load_lds(
        (const __attribute__((address_space(1))) unsigned int*)(const void*)g,
        (__attribute__((address_space(3))) unsigned int*)(void*)l, 16, 0, 0);
}

// ---------- Pre-pass: Bt[kt][n][slot*8 + k&7] bf16 + wrelu ----------
__global__ void convert_W(const float* __restrict__ w_ih,
                          const float* __restrict__ w_ho,
                          u16* __restrict__ Bt, float* __restrict__ wrelu) {
    if (blockIdx.x == NK * 32) {
        for (int i = threadIdx.x; i < NH * NO; i += 256)
            wrelu[i] = fmaxf(0.f, w_ho[i]);
        return;
    }
    const int k = blockIdx.x;           // 0..799
    const int n = threadIdx.x;          // 0..255
    const float f = (k < NIN) ? fmaxf(0.f, w_ih[k * NH + n]) : 0.f;
    const int kt = k >> 5, kk = k & 31;
    const int slot = (kk >> 3) ^ (n & 3) ^ ((n >> 2) & 3);
    Bt[(size_t)kt * 8192 + n * 32 + slot * 8 + (kk & 7)] = f2bf(f);
}

// ---------- hidden GEMM: 256m x 256n, 1KB A-runs, counted barriers ----------
__global__ __launch_bounds__(1024, 4) void gemm_hidden(
    const float* __restrict__ spikes,   // [128][784][500] f32
    const u16* __restrict__ Bt,         // [25][256][32] bf16 swizzled
    u16* __restrict__ Ih)               // [128][256][512] bf16
{
    __shared__ u16 SH[32768];           // 64KB
    u16* AS0 = SH;                      // 8192 u16 = 16KB each
    u16* AS1 = SH + 8192;
    u16* BS0 = SH + 16384;
    u16* BS1 = SH + 24576;

    const int tid = threadIdx.x;
    // XCD pair-swizzle (grid 256 = 32 slots x 8 XCDs, bijective):
    const int xcd  = blockIdx.x & 7;
    const int slot = blockIdx.x >> 3;   // 0..31
    const int b    = xcd * 16 + (slot >> 1);
    const int th   = slot & 1;
    const int t0   = th * 256;

    const int kq = tid >> 6, tg = tid & 63;
    const int tloc = t0 + tg * 4;
    const bool t_ok = (tloc <= 496);
    const float* sbase = spikes + (size_t)b * (NIN * T_) + tloc;
    const int oct  = kq >> 2;
    const int koff = (2 * kq) & 7;

    const int lane = tid & 63, wid = tid >> 6;
    const int wm = wid >> 2, wn = wid & 3;
    const int lg = lane >> 4, lr = lane & 15;
    int aOff[4], bOff[4];
#pragma unroll
    for (int mi = 0; mi < 4; ++mi) {
        const int m = wm * 64 + mi * 16 + lr;
        aOff[mi] = m * 32 + ((lg ^ (m & 3) ^ ((m >> 2) & 3)) << 3);
    }
#pragma unroll
    for (int ni = 0; ni < 4; ++ni) {
        const int n = wn * 64 + ni * 16 + lr;
        bOff[ni] = n * 32 + ((lg ^ (n & 3) ^ ((n >> 2) & 3)) << 3);
    }

    floatx4 acc[4][4];
#pragma unroll
    for (int i = 0; i < 4; ++i)
#pragma unroll
        for (int j = 0; j < 4; ++j) acc[i][j] = (floatx4)0.f;

#define LOADA(v0, v1, itv) {                                                   \
        const int gk = (itv) * 32 + 2 * kq;                                    \
        const bool ok0 = t_ok && (gk < NIN);                                   \
        const bool ok1 = t_ok && (gk + 1 < NIN);                               \
        const float* p0 = ok0 ? (sbase + (size_t)gk * T_) : sbase;             \
        const float* p1 = ok1 ? (sbase + (size_t)(gk + 1) * T_) : sbase;       \
        floatx4 u0 = *(const floatx4*)p0;                                      \
        floatx4 u1 = *(const floatx4*)p1;                                      \
        v0 = ok0 ? u0 : (floatx4)0.f;                                          \
        v1 = ok1 ? u1 : (floatx4)0.f; }

#define WRITEA(ASX, v0, v1) { _Pragma("unroll") for (int j = 0; j < 4; ++j) {  \
        const int m = tg * 4 + j;                                              \
        const int slt = oct ^ (m & 3) ^ ((m >> 2) & 3);                        \
        const u32 pk = (u32)f2bf(v0[j]) | ((u32)f2bf(v1[j]) << 16);            \
        *(u32*)&(ASX)[m * 32 + slt * 8 + koff] = pk; } }

#define STAGEB(BSX, itv)                                                       \
        gload16(Bt + (size_t)(itv) * 8192 + tid * 8, (BSX) + tid * 8);

#define MFMAIT(ASX, BSX) { shortx8 af[4], bf[4];                               \
        _Pragma("unroll") for (int mi = 0; mi < 4; ++mi)                       \
            af[mi] = *(const shortx8*)&(ASX)[aOff[mi]];                        \
        _Pragma("unroll") for (int ni = 0; ni < 4; ++ni)                       \
            bf[ni] = *(const shortx8*)&(BSX)[bOff[ni]];                        \
        _Pragma("unroll") for (int mi = 0; mi < 4; ++mi)                       \
        _Pragma("unroll") for (int ni = 0; ni < 4; ++ni)                       \
            acc[mi][ni] = __builtin_amdgcn_mfma_f32_16x16x32_bf16(             \
                af[mi], bf[ni], acc[mi][ni], 0, 0, 0); }

#define CBAR2 { asm volatile("s_waitcnt vmcnt(2) lgkmcnt(0)" ::: "memory");    \
                __builtin_amdgcn_s_barrier(); }
#define LBAR  { asm volatile("s_waitcnt lgkmcnt(0)" ::: "memory");             \
                __builtin_amdgcn_s_barrier(); }

    floatx4 vaP0, vaP1;

    LOADA(vaP0, vaP1, 0);
    WRITEA(AS0, vaP0, vaP1);
    STAGEB(BS0, 0);
    LOADA(vaP0, vaP1, 1);
    CBAR2;

    for (int it = 0; it < 24; it += 2) {
        STAGEB(BS1, it + 1);
        WRITEA(AS1, vaP0, vaP1);
        { const int nv = (it + 2 < 24) ? (it + 2) : 24;
          LOADA(vaP0, vaP1, nv); }
        MFMAIT(AS0, BS0);
        CBAR2;

        STAGEB(BS0, it + 2);
        WRITEA(AS0, vaP0, vaP1);
        { const int nv = (it + 3 < 24) ? (it + 3) : 24;
          LOADA(vaP0, vaP1, nv); }
        MFMAIT(AS1, BS1);
        CBAR2;
    }
    MFMAIT(AS0, BS0);                   // tile 24
    LBAR;

    // epilogue: 4 wm-rounds via Cs[256 n][64 m] (32KB, aliases SH)
    u16* Cs = SH;
#pragma unroll
    for (int h = 0; h < 4; ++h) {
        if (wm == h) {
#pragma unroll
            for (int mi = 0; mi < 4; ++mi)
#pragma unroll
                for (int rr = 0; rr < 2; ++rr) {
                    const int mloc = mi * 16 + lg * 4 + rr * 2;
#pragma unroll
                    for (int ni = 0; ni < 4; ++ni) {
                        const int n = wn * 64 + ni * 16 + lr;
                        const u32 pk = (u32)f2bf(acc[mi][ni][rr * 2]) |
                                       ((u32)f2bf(acc[mi][ni][rr * 2 + 1]) << 16);
                        *(u32*)&Cs[n * 64 + (mloc ^ ((n & 7) << 3))] = pk;
                    }
                }
        }
        LBAR;
        {
            const int n = tid >> 2, ms = tid & 3;
            u16* gdst = Ih + ((size_t)b * 256 + n) * 512 + t0 + h * 64 + ms * 16;
#pragma unroll
            for (int j = 0; j < 2; ++j) {
                const uint4 v = *(const uint4*)&Cs[n * 64 +
                                ((ms * 16 + j * 8) ^ ((n & 7) << 3))];
                *(uint4*)(gdst + j * 8) = v;
            }
        }
        LBAR;
    }
#undef LOADA
#undef WRITEA
#undef STAGEB
#undef MFMAIT
#undef CBAR2
#undef LBAR
}

// ---------- fused: parallel hidden LIF scan + output dot ----------
__global__ __launch_bounds__(512, 2) void scan_dot(
    const u16* __restrict__ Ih,         // [128][256][512] bf16
    const float* __restrict__ wr,       // [256][10] relu'd f32
    float* __restrict__ IoP)            // [128][512][4][10] f32
{
    __shared__ u16 sbuf[64 * SROW];     // 66.6KB
    const int tid = threadIdx.x;
    const int hg  = blockIdx.x & 3;
    const int b   = blockIdx.x >> 2;
    const int h0  = hg * 64;
    const int lane = tid & 63, w = tid >> 6;

    // ---- phase 1: scan 8 rows per wave ----
    for (int r = 0; r < 8; ++r) {
        const int hl = w * 8 + r;
        const u16* p = Ih + ((size_t)b * 256 + h0 + hl) * 512 + lane * 8;
        shortx8 xv = *(const shortx8*)p;
        float I[8];
#pragma unroll
        for (int j = 0; j < 8; ++j) I[j] = bf2f((u16)xv[j]);
        float z = 0.f;
#pragma unroll
        for (int j = 0; j < 8; ++j) z += (I[j] - z) * 0.1f;
        float A = 0.43046721f, Bv = z;             // 0.9^8
#pragma unroll
        for (int d = 1; d < 64; d <<= 1) {
            const float Au = __shfl_up(A, d);
            const float Bu = __shfl_up(Bv, d);
            if (lane >= d) { Bv = fmaf(A, Bu, Bv); A *= Au; }
        }
        float v = __shfl_up(Bv, 1);
        if (lane == 0) v = 0.f;
        shortx8 sv;
#pragma unroll
        for (int j = 0; j < 8; ++j) {
            v += (I[j] - v) * 0.1f;
            sv[j] = (short)f2bf(sigmoid5(v));
        }
        *(shortx8*)&sbuf[hl * SROW + lane * 8] = sv;
    }
    __syncthreads();

    // ---- phase 2: dot via MFMA.  A[m=t][k=hl], B[k=hl][n=o] ----
    const int lg = lane >> 4, lr = lane & 15;
    shortx8 bw0, bw1;
#pragma unroll
    for (int j = 0; j < 8; ++j) {
        const int hA = h0 + lg * 8 + j;
        const int hB = hA + 32;
        bw0[j] = (short)((lr < NO) ? f2bf(wr[hA * NO + lr]) : 0);
        bw1[j] = (short)((lr < NO) ? f2bf(wr[hB * NO + lr]) : 0);
    }
#pragma unroll
    for (int fi = 0; fi < 4; ++fi) {
        const int tf = w * 4 + fi;
        const int t  = tf * 16 + lr;
        floatx4 acc = (floatx4)0.f;
#pragma unroll
        for (int ks = 0; ks < 2; ++ks) {
            union { shortx8 s; u32 d[4]; } u;
#pragma unroll
            for (int q = 0; q < 4; ++q) {
                const int h1 = ks * 32 + lg * 8 + 2 * q;
                u.d[q] = (u32)sbuf[h1 * SROW + t] |
                         ((u32)sbuf[(h1 + 1) * SROW + t] << 16);
            }
            acc = __builtin_amdgcn_mfma_f32_16x16x32_bf16(
                u.s, (ks == 0) ? bw0 : bw1, acc, 0, 0, 0);
        }
        if (lr < NO) {
#pragma unroll
            for (int rr = 0; rr < 4; ++rr) {
                const int tt = tf * 16 + lg * 4 + rr;
                IoP[(((size_t)b * 512 + tt) * 4 + hg) * NO + lr] = acc[rr];
            }
        }
    }
}

// ---------- output LIF scan: sum 4 partials + segmented scan ----------
__global__ __launch_bounds__(256) void lif_out(
    const float* __restrict__ IoP,      // [128][512][4][10] f32
    float* __restrict__ out)
{
    __shared__ float Io[T_ * NO];       // 20KB
    __shared__ float vend[25][NO], vstart[25][NO], psum[25][NO];
    const int b = blockIdx.x, tid = threadIdx.x;

    for (int i = tid; i < T_ * NO; i += 256) {
        const int t = i / NO, o = i - t * NO;
        const float* q = IoP + ((size_t)b * 512 + t) * 40 + o;
        Io[i] = (q[0] + q[10]) + (q[20] + q[30]);
    }
    __syncthreads();

    const int seg = tid / NO, o = tid - seg * NO;
    if (tid < 250) {
        float v = 0.f;
#pragma unroll
        for (int j = 0; j < 20; ++j)
            v += (Io[(seg * 20 + j) * NO + o] - v) * 0.1f;
        vend[seg][o] = v;
    }
    __syncthreads();
    if (tid < NO) {
        float vs = 0.f;
#pragma unroll
        for (int sg = 0; sg < 25; ++sg) {
            vstart[sg][tid] = vs;
            vs = vend[sg][tid] + 0.12157665459f * vs;   // 0.9^20
        }
    }
    __syncthreads();
    if (tid < 250) {
        float v = vstart[seg][o], ps = 0.f;
#pragma unroll
        for (int j = 0; j < 20; ++j) {
            const int t = seg * 20 + j;
            v += (Io[t * NO + o] - v) * 0.1f;
            const float sv = sigmoid5(v);
            out[(size_t)b * (NO * T_) + (size_t)o * T_ + t] = sv;
            ps += sv;
        }
        psum[seg][o] = ps;
    }
    __syncthreads();
    if (tid < NO) {
        float tot = 0.f;
#pragma unroll
        for (int sg = 0; sg < 25; ++sg) tot += psum[sg][tid];
        out[(size_t)(B_ * NO) * T_ + b * NO + tid] = tot * (1.0f / T_);
    }
}

extern "C" void kernel_launch(void* const* d_in, const int* in_sizes, int n_in,
                              void* d_out, int out_size, void* d_ws, size_t ws_size,
                              hipStream_t stream) {
    (void)in_sizes; (void)n_in; (void)out_size; (void)ws_size;
    const float* spikes = (const float*)d_in[0];   // [128][784][500]
    const float* w_ih   = (const float*)d_in[1];   // [784][256]
    const float* w_ho   = (const float*)d_in[2];   // [256][10]
    float* out = (float*)d_out;

    float* wrelu = (float*)d_ws;                              // 10KB @0
    u16*   Bt    = (u16*)((char*)d_ws + 16384);               // 400KB
    u16*   Ih    = (u16*)((char*)d_ws + 524288);              // 33.55MB
    float* IoP   = (float*)((char*)d_ws + 524288 + 33554432); // 10.49MB

    convert_W  <<<NK * 32 + 1, 256, 0, stream>>>(w_ih, w_ho, Bt, wrelu);
    gemm_hidden<<<256, 1024, 0, stream>>>(spikes, Bt, Ih);
    scan_dot   <<<512, 512, 0, stream>>>(Ih, wrelu, IoP);
    lif_out    <<<B_, 256, 0, stream>>>(IoP, out);
}